// Round 4
// baseline (362.927 us; speedup 1.0000x reference)
//
#include <hip/hip_runtime.h>

typedef __attribute__((ext_vector_type(4))) float f32x4;
typedef __attribute__((ext_vector_type(8))) short bf16x8;

#define BM 256
#define BN 256
#define BK 32
// per-matrix per-tile LDS: 256 rows x 32 cols x 2B = 16384 B = 8192 ushorts

static __device__ __forceinline__ ushort f2b(float f) {
    uint u = __float_as_uint(f);
    uint r = (u + 0x7fffu + ((u >> 16) & 1u)) >> 16;
    return (ushort)r;
}
static __device__ __forceinline__ float b2f(ushort h) {
    return __uint_as_float(((uint)h) << 16);
}

// ---------------- fp32 -> bf16 convert (vectorized, grid-stride) -------------
__global__ __launch_bounds__(256) void f2b_kernel(const float* __restrict__ in,
                                                  ushort* __restrict__ out, int n4) {
    int i = blockIdx.x * blockDim.x + threadIdx.x;
    int stride = gridDim.x * blockDim.x;
    for (; i < n4; i += stride) {
        float4 v = ((const float4*)in)[i];
        ushort4 o;
        o.x = f2b(v.x); o.y = f2b(v.y); o.z = f2b(v.z); o.w = f2b(v.w);
        ((ushort4*)out)[i] = o;
    }
}

// ---------------- fused QKV GEMM: C_{q,k,v} = x * W_cat^T -------------------
// 256x256 tile, ring-4 LDS, stage-ahead 3, 2 pinned phases per K-tile.
// LDS swizzle g(r,c16) = ((r<<6)|(c16<<4)) ^ ((r&7)<<4); global_load_lds
// writes LINEAR dest, global SOURCE pre-inverse-swizzled (rule #21).
__device__ __forceinline__ void stage_mat(
    const ushort* __restrict__ G, ushort* Ls, int tt, int rc0,
    int r0, int c0, int r1, int c1, int w) {
    const int K = 1024;
    int buf = tt & 3;
    int k0 = tt * BK;
    ushort* l0 = Ls + buf * 8192 + (w << 6) * 8;
    ushort* l1 = Ls + buf * 8192 + (512 + (w << 6)) * 8;
    const ushort* g0 = G + (size_t)(rc0 + r0) * K + k0 + c0 * 8;
    const ushort* g1 = G + (size_t)(rc0 + r1) * K + k0 + c1 * 8;
    __builtin_amdgcn_global_load_lds((const __attribute__((address_space(1))) void*)g0,
                                     (__attribute__((address_space(3))) void*)l0, 16, 0, 0);
    __builtin_amdgcn_global_load_lds((const __attribute__((address_space(1))) void*)g1,
                                     (__attribute__((address_space(3))) void*)l1, 16, 0, 0);
}

__global__ __launch_bounds__(512, 2) void gemm_qkv(const ushort* __restrict__ A,
                                                   const ushort* __restrict__ Wcat,
                                                   ushort* __restrict__ Cq,
                                                   ushort* __restrict__ Ck,
                                                   ushort* __restrict__ Cv) {
    __shared__ ushort As[4 * 8192];  // 64 KiB
    __shared__ ushort Bs[4 * 8192];  // 64 KiB
    const int K = 1024, CTN = 12;

    // T1: XCD-chunked swizzle (nwg = 1536, divisible by 8)
    int nwg = gridDim.x;
    int cpx = nwg >> 3;
    int bid = blockIdx.x;
    int orig = (bid & 7) * cpx + (bid >> 3);
    int rt = orig / CTN, ct = orig % CTN;
    int row0 = rt * BM, col0 = ct * BN;  // col0 = row offset in Wcat

    int t = threadIdx.x, l = t & 63, w = t >> 6;
    int wr = w >> 2, wc = w & 3;       // wave grid 2 (M) x 4 (N)
    int lr = l & 15, c16 = l >> 4;

    // staging geometry: invert g() for this thread's two 16B chunks
    int r_[2], c_[2];
#pragma unroll
    for (int i = 0; i < 2; ++i) {
        int d = (i * 512 + t) * 16;
        int rr = ((d >> 6) & ~1) | (((d >> 6) ^ (d >> 8)) & 1);
        r_[i] = rr;
        c_[i] = ((d >> 4) & 3) ^ (rr & 3);
    }

    // fragment read bases (byte offsets within one 16 KiB tile)
    int mask = (lr & 7) << 4;
    int baseA = ((((wr * 128 + lr) << 6) | (c16 << 4)) ^ mask);
    int baseB = ((((wc * 64 + lr) << 6) | (c16 << 4)) ^ mask);

    f32x4 acc[8][4] = {};

    const int NT = 32;  // K / BK
    stage_mat(A, As, 0, row0, r_[0], c_[0], r_[1], c_[1], w);
    stage_mat(Wcat, Bs, 0, col0, r_[0], c_[0], r_[1], c_[1], w);
    stage_mat(A, As, 1, row0, r_[0], c_[0], r_[1], c_[1], w);
    stage_mat(Wcat, Bs, 1, col0, r_[0], c_[0], r_[1], c_[1], w);
    stage_mat(A, As, 2, row0, r_[0], c_[0], r_[1], c_[1], w);
    stage_mat(Wcat, Bs, 2, col0, r_[0], c_[0], r_[1], c_[1], w);
    asm volatile("s_waitcnt vmcnt(8)" ::: "memory");  // tile 0 landed
    __builtin_amdgcn_s_barrier();

    for (int tt = 0; tt < NT; ++tt) {
        const char* At = (const char*)As + (tt & 3) * 16384;
        const char* Bt = (const char*)Bs + (tt & 3) * 16384;
        bf16x8 a0[4], a1[4], b[4];

        // ---- phase A: read a[0:4], b[0:4]; stage next A; 16 MFMA ----
#pragma unroll
        for (int m = 0; m < 4; ++m)
            a0[m] = *(const bf16x8*)(At + baseA + m * 1024);
#pragma unroll
        for (int n = 0; n < 4; ++n)
            b[n] = *(const bf16x8*)(Bt + baseB + n * 1024);
        if (tt + 3 < NT)
            stage_mat(A, As, tt + 3, row0, r_[0], c_[0], r_[1], c_[1], w);
        __builtin_amdgcn_sched_barrier(0);
        __builtin_amdgcn_s_barrier();
        asm volatile("s_waitcnt lgkmcnt(0)" ::: "memory");
        __builtin_amdgcn_sched_barrier(0);
        __builtin_amdgcn_s_setprio(1);
#pragma unroll
        for (int m = 0; m < 4; ++m)
#pragma unroll
            for (int n = 0; n < 4; ++n)
                acc[m][n] = __builtin_amdgcn_mfma_f32_16x16x32_bf16(a0[m], b[n], acc[m][n], 0, 0, 0);
        __builtin_amdgcn_s_setprio(0);
        __builtin_amdgcn_sched_barrier(0);
        __builtin_amdgcn_s_barrier();

        // ---- phase B: read a[4:8]; stage next B; vmcnt; 16 MFMA ----
#pragma unroll
        for (int m = 0; m < 4; ++m)
            a1[m] = *(const bf16x8*)(At + baseA + (m + 4) * 1024);
        if (tt + 3 < NT)
            stage_mat(Wcat, Bs, tt + 3, col0, r_[0], c_[0], r_[1], c_[1], w);
        // guarantee tile tt+1 landed for next phase A (newer: tiles tt+2,tt+3)
        if (tt <= NT - 4)      asm volatile("s_waitcnt vmcnt(8)" ::: "memory");
        else if (tt == NT - 3) asm volatile("s_waitcnt vmcnt(4)" ::: "memory");
        else if (tt == NT - 2) asm volatile("s_waitcnt vmcnt(0)" ::: "memory");
        __builtin_amdgcn_sched_barrier(0);
        __builtin_amdgcn_s_barrier();
        asm volatile("s_waitcnt lgkmcnt(0)" ::: "memory");
        __builtin_amdgcn_sched_barrier(0);
        __builtin_amdgcn_s_setprio(1);
#pragma unroll
        for (int m = 0; m < 4; ++m)
#pragma unroll
            for (int n = 0; n < 4; ++n)
                acc[m + 4][n] = __builtin_amdgcn_mfma_f32_16x16x32_bf16(a1[m], b[n], acc[m + 4][n], 0, 0, 0);
        __builtin_amdgcn_s_setprio(0);
        __builtin_amdgcn_sched_barrier(0);
        __builtin_amdgcn_s_barrier();
    }

    // output buffer select: ct 0-3 -> Q, 4-7 -> K, 8-11 -> V
    int q = ct >> 2;
    ushort* Cb = (q == 0) ? Cq : ((q == 1) ? Ck : Cv);
    int colc = (ct & 3) * 256;

    // epilogue: C/D layout col=lane&15, row=(lane>>4)*4+reg
#pragma unroll
    for (int m = 0; m < 8; ++m) {
        int gr = row0 + wr * 128 + m * 16 + c16 * 4;
#pragma unroll
        for (int n = 0; n < 4; ++n) {
            int gc = colc + wc * 64 + n * 16 + lr;
#pragma unroll
            for (int j = 0; j < 4; ++j)
                Cb[(size_t)(gr + j) * 1024 + gc] = f2b(acc[m][n][j]);
        }
    }
}

// ---------------- gf[b,e] = mean_n( l2norm(K_pre)[n,e] * V[n,e] ) -----------
// Wave-local: one row per wave per iteration, no per-row __syncthreads.
__global__ __launch_bounds__(256) void kv_reduce(const ushort* __restrict__ Kp,
                                                 const ushort* __restrict__ Vp,
                                                 float* __restrict__ gf) {
    const int D = 1024, N = 4096;
    int b = blockIdx.y;
    int t = threadIdx.x, l = t & 63, w = t >> 6;
    int r0 = blockIdx.x * 128 + w * 32;  // gridDim.x = 32, 4 waves x 32 rows
    __shared__ float part[4][1024];

    float acc[2][8] = {};
    for (int r = 0; r < 32; ++r) {
        size_t row = (size_t)b * N + r0 + r;
        bf16x8 kv0 = *(const bf16x8*)&Kp[row * D + l * 8];
        bf16x8 kv1 = *(const bf16x8*)&Kp[row * D + l * 8 + 512];
        bf16x8 vv0 = *(const bf16x8*)&Vp[row * D + l * 8];
        bf16x8 vv1 = *(const bf16x8*)&Vp[row * D + l * 8 + 512];
        float kf0[8], kf1[8], ss = 0.f;
#pragma unroll
        for (int j = 0; j < 8; ++j) {
            kf0[j] = b2f((ushort)kv0[j]);
            kf1[j] = b2f((ushort)kv1[j]);
            ss += kf0[j] * kf0[j] + kf1[j] * kf1[j];
        }
#pragma unroll
        for (int off = 32; off; off >>= 1) ss += __shfl_xor(ss, off);
        float inv = 1.0f / fmaxf(sqrtf(ss), 1e-12f);
#pragma unroll
        for (int j = 0; j < 8; ++j) {
            acc[0][j] += kf0[j] * inv * b2f((ushort)vv0[j]);
            acc[1][j] += kf1[j] * inv * b2f((ushort)vv1[j]);
        }
    }
#pragma unroll
    for (int i = 0; i < 2; ++i)
#pragma unroll
        for (int j = 0; j < 8; ++j)
            part[w][l * 8 + i * 512 + j] = acc[i][j];
    __syncthreads();
    const float sc = 1.0f / 4096.0f;
#pragma unroll
    for (int i = 0; i < 4; ++i) {
        int c = t * 4 + i;
        float s = part[0][c] + part[1][c] + part[2][c] + part[3][c];
        atomicAdd(&gf[b * D + c], s * sc);
    }
}

// ---------------- out[row,e] = l2norm(Q_pre)[row,e] * gf[b,e]  (fp32 out) ---
__global__ __launch_bounds__(256) void q_scale(const ushort* __restrict__ Qp,
                                               const float* __restrict__ gf,
                                               float* __restrict__ out) {
    const int D = 1024;
    int row = blockIdx.x * 4 + (threadIdx.x >> 6);
    int l = threadIdx.x & 63;
    int b = row >> 12;  // N = 4096
    const ushort* qr = &Qp[(size_t)row * D];
    float qf[4][4];
    float ss = 0.f;
#pragma unroll
    for (int i = 0; i < 4; ++i) {
        ushort4 q = *(const ushort4*)&qr[l * 4 + i * 256];
        qf[i][0] = b2f(q.x); qf[i][1] = b2f(q.y);
        qf[i][2] = b2f(q.z); qf[i][3] = b2f(q.w);
        ss += qf[i][0] * qf[i][0] + qf[i][1] * qf[i][1] +
              qf[i][2] * qf[i][2] + qf[i][3] * qf[i][3];
    }
#pragma unroll
    for (int off = 32; off; off >>= 1) ss += __shfl_xor(ss, off);
    float inv = 1.0f / fmaxf(sqrtf(ss), 1e-12f);
#pragma unroll
    for (int i = 0; i < 4; ++i) {
        float4 g = *(const float4*)&gf[b * D + l * 4 + i * 256];
        float4 o;
        o.x = qf[i][0] * inv * g.x;
        o.y = qf[i][1] * inv * g.y;
        o.z = qf[i][2] * inv * g.z;
        o.w = qf[i][3] * inv * g.w;
        *(float4*)&out[(size_t)row * D + l * 4 + i * 256] = o;
    }
}

extern "C" void kernel_launch(void* const* d_in, const int* in_sizes, int n_in,
                              void* d_out, int out_size, void* d_ws, size_t ws_size,
                              hipStream_t stream) {
    const float* x  = (const float*)d_in[0];
    const float* Wq = (const float*)d_in[1];
    const float* Wk = (const float*)d_in[2];
    const float* Wv = (const float*)d_in[3];
    float* out = (float*)d_out;

    const int Bb = 8, Nn = 4096, D = 1024;
    const int M = Bb * Nn;  // 32768 rows

    char* ws = (char*)d_ws;
    ushort* xb  = (ushort*)ws;                         // 67108864 B
    ushort* wqb = (ushort*)(ws + 67108864);            // 2097152 B  } contiguous
    ushort* wkb = (ushort*)(ws + 69206016);            // 2097152 B  } = W_cat
    ushort* wvb = (ushort*)(ws + 71303168);            // 2097152 B  } [3072][1024]
    ushort* P1  = (ushort*)(ws + 73400320);            // 67108864 B (Q_pre)
    float*  gf  = (float*)(ws + 140509184);            // 32768 B

    // d_out (134.2 MB) doubles as bf16 scratch for K_pre / V until q_scale.
    ushort* Kp = (ushort*)d_out;
    ushort* Vp = Kp + (size_t)M * D;

    hipMemsetAsync(gf, 0, Bb * D * sizeof(float), stream);

    f2b_kernel<<<2048, 256, 0, stream>>>(x, xb, (M * D) / 4);
    f2b_kernel<<<256, 256, 0, stream>>>(Wq, wqb, (D * D) / 4);
    f2b_kernel<<<256, 256, 0, stream>>>(Wk, wkb, (D * D) / 4);
    f2b_kernel<<<256, 256, 0, stream>>>(Wv, wvb, (D * D) / 4);

    gemm_qkv<<<(M / BM) * 12, 512, 0, stream>>>(xb, wqb, P1, Kp, Vp);
    kv_reduce<<<dim3(32, 8), 256, 0, stream>>>(Kp, Vp, gf);
    q_scale<<<M / 4, 256, 0, stream>>>(P1, gf, out);
}

// Round 5
// 353.269 us; speedup vs baseline: 1.0273x; 1.0273x over previous
//
#include <hip/hip_runtime.h>

typedef __attribute__((ext_vector_type(4))) float f32x4;
typedef __attribute__((ext_vector_type(8))) short bf16x8;

#define BM 256
#define BN 256
#define BK 32
// per-matrix per-tile LDS: 256 rows x 32 cols x 2B = 16384 B = 8192 ushorts

static __device__ __forceinline__ ushort f2b(float f) {
    uint u = __float_as_uint(f);
    uint r = (u + 0x7fffu + ((u >> 16) & 1u)) >> 16;
    return (ushort)r;
}
static __device__ __forceinline__ float b2f(ushort h) {
    return __uint_as_float(((uint)h) << 16);
}

// ---------------- fp32 -> bf16 convert (vectorized, grid-stride) -------------
__global__ __launch_bounds__(256) void f2b_kernel(const float* __restrict__ in,
                                                  ushort* __restrict__ out, int n4) {
    int i = blockIdx.x * blockDim.x + threadIdx.x;
    int stride = gridDim.x * blockDim.x;
    for (; i < n4; i += stride) {
        float4 v = ((const float4*)in)[i];
        ushort4 o;
        o.x = f2b(v.x); o.y = f2b(v.y); o.z = f2b(v.z); o.w = f2b(v.w);
        ((ushort4*)out)[i] = o;
    }
}

// ---------------- bf16 GEMM, C = A * B^T  (A: Mx1024, Bw: 1024x1024) -------
// 256x256 tile, ring-4 LDS, stage-ahead 3, 2 pinned phases per K-tile.
// All 12 ds_reads issued in phase A (compiler inserts lgkmcnt(4) for the
// first 8); phase B's MFMA needs no LDS wait -> overlaps staging + vmcnt.
// LDS swizzle g(r,c16) = ((r<<6)|(c16<<4)) ^ ((r&7)<<4); global_load_lds
// writes LINEAR dest, global SOURCE pre-inverse-swizzled (rule #21).
__device__ __forceinline__ void stage_mat(
    const ushort* __restrict__ G, ushort* Ls, int tt, int rc0,
    int r0, int c0, int r1, int c1, int w) {
    const int K = 1024;
    int buf = tt & 3;
    int k0 = tt * BK;
    ushort* l0 = Ls + buf * 8192 + (w << 6) * 8;
    ushort* l1 = Ls + buf * 8192 + (512 + (w << 6)) * 8;
    const ushort* g0 = G + (size_t)(rc0 + r0) * K + k0 + c0 * 8;
    const ushort* g1 = G + (size_t)(rc0 + r1) * K + k0 + c1 * 8;
    __builtin_amdgcn_global_load_lds((const __attribute__((address_space(1))) void*)g0,
                                     (__attribute__((address_space(3))) void*)l0, 16, 0, 0);
    __builtin_amdgcn_global_load_lds((const __attribute__((address_space(1))) void*)g1,
                                     (__attribute__((address_space(3))) void*)l1, 16, 0, 0);
}

__global__ __launch_bounds__(512, 2) void gemm_bt3(const ushort* __restrict__ A,
                                                   const ushort* __restrict__ Bw,
                                                   ushort* __restrict__ C) {
    __shared__ ushort As[4 * 8192];  // 64 KiB
    __shared__ ushort Bs[4 * 8192];  // 64 KiB
    const int CTN = 4;  // 1024 / BN

    // T1: XCD-chunked swizzle (nwg = 512, divisible by 8)
    int nwg = gridDim.x;
    int cpx = nwg >> 3;
    int bid = blockIdx.x;
    int orig = (bid & 7) * cpx + (bid >> 3);
    int rt = orig / CTN, ct = orig % CTN;
    int row0 = rt * BM, col0 = ct * BN;

    int t = threadIdx.x, l = t & 63, w = t >> 6;
    int wr = w >> 2, wc = w & 3;       // wave grid 2 (M) x 4 (N)
    int lr = l & 15, c16 = l >> 4;

    // staging geometry: invert g() for this thread's two 16B chunks
    int r_[2], c_[2];
#pragma unroll
    for (int i = 0; i < 2; ++i) {
        int d = (i * 512 + t) * 16;
        int rr = ((d >> 6) & ~1) | (((d >> 6) ^ (d >> 8)) & 1);
        r_[i] = rr;
        c_[i] = ((d >> 4) & 3) ^ (rr & 3);
    }

    // fragment read bases (byte offsets within one 16 KiB tile)
    int mask = (lr & 7) << 4;
    int baseA = ((((wr * 128 + lr) << 6) | (c16 << 4)) ^ mask);
    int baseB = ((((wc * 64 + lr) << 6) | (c16 << 4)) ^ mask);

    f32x4 acc[8][4] = {};

    const int NT = 32;  // K / BK
    stage_mat(A, As, 0, row0, r_[0], c_[0], r_[1], c_[1], w);
    stage_mat(Bw, Bs, 0, col0, r_[0], c_[0], r_[1], c_[1], w);
    stage_mat(A, As, 1, row0, r_[0], c_[0], r_[1], c_[1], w);
    stage_mat(Bw, Bs, 1, col0, r_[0], c_[0], r_[1], c_[1], w);
    stage_mat(A, As, 2, row0, r_[0], c_[0], r_[1], c_[1], w);
    stage_mat(Bw, Bs, 2, col0, r_[0], c_[0], r_[1], c_[1], w);
    asm volatile("s_waitcnt vmcnt(8)" ::: "memory");  // tile 0 landed
    __builtin_amdgcn_s_barrier();

    for (int tt = 0; tt < NT; ++tt) {
        const char* At = (const char*)As + (tt & 3) * 16384;
        const char* Bt = (const char*)Bs + (tt & 3) * 16384;
        bf16x8 a0[4], a1[4], b[4];

        // ---- phase A: read ALL 12 frags; stage next A; 16 MFMA (a0 x b) ----
#pragma unroll
        for (int m = 0; m < 4; ++m)
            a0[m] = *(const bf16x8*)(At + baseA + m * 1024);
#pragma unroll
        for (int n = 0; n < 4; ++n)
            b[n] = *(const bf16x8*)(Bt + baseB + n * 1024);
#pragma unroll
        for (int m = 0; m < 4; ++m)
            a1[m] = *(const bf16x8*)(At + baseA + (m + 4) * 1024);
        if (tt + 3 < NT)
            stage_mat(A, As, tt + 3, row0, r_[0], c_[0], r_[1], c_[1], w);
        __builtin_amdgcn_sched_barrier(0);
        __builtin_amdgcn_s_barrier();
        __builtin_amdgcn_s_setprio(1);
#pragma unroll
        for (int m = 0; m < 4; ++m)
#pragma unroll
            for (int n = 0; n < 4; ++n)
                acc[m][n] = __builtin_amdgcn_mfma_f32_16x16x32_bf16(a0[m], b[n], acc[m][n], 0, 0, 0);
        __builtin_amdgcn_s_setprio(0);
        __builtin_amdgcn_sched_barrier(0);
        __builtin_amdgcn_s_barrier();

        // ---- phase B: stage next B; vmcnt; 16 MFMA (a1 x b) — no LDS wait ----
        if (tt + 3 < NT)
            stage_mat(Bw, Bs, tt + 3, col0, r_[0], c_[0], r_[1], c_[1], w);
        // guarantee tile tt+1 landed for next phase A (newer: tiles tt+2,tt+3)
        if (tt <= NT - 4)      asm volatile("s_waitcnt vmcnt(8)" ::: "memory");
        else if (tt == NT - 3) asm volatile("s_waitcnt vmcnt(4)" ::: "memory");
        else if (tt == NT - 2) asm volatile("s_waitcnt vmcnt(0)" ::: "memory");
        __builtin_amdgcn_sched_barrier(0);
        __builtin_amdgcn_s_barrier();
        __builtin_amdgcn_s_setprio(1);
#pragma unroll
        for (int m = 0; m < 4; ++m)
#pragma unroll
            for (int n = 0; n < 4; ++n)
                acc[m + 4][n] = __builtin_amdgcn_mfma_f32_16x16x32_bf16(a1[m], b[n], acc[m + 4][n], 0, 0, 0);
        __builtin_amdgcn_s_setprio(0);
        __builtin_amdgcn_sched_barrier(0);
        __builtin_amdgcn_s_barrier();
    }

    // epilogue: C/D layout col=lane&15, row=(lane>>4)*4+reg
#pragma unroll
    for (int m = 0; m < 8; ++m) {
        int gr = row0 + wr * 128 + m * 16 + c16 * 4;
#pragma unroll
        for (int n = 0; n < 4; ++n) {
            int gc = col0 + wc * 64 + n * 16 + lr;
#pragma unroll
            for (int j = 0; j < 4; ++j)
                C[(size_t)(gr + j) * 1024 + gc] = f2b(acc[m][n][j]);
        }
    }
}

// ---------------- gf[b,e] = mean_n( l2norm(K_pre)[n,e] * V[n,e] ) -----------
// Wave-local: one row per wave per iteration, no per-row __syncthreads.
__global__ __launch_bounds__(256) void kv_reduce(const ushort* __restrict__ Kp,
                                                 const ushort* __restrict__ Vp,
                                                 float* __restrict__ gf) {
    const int D = 1024, N = 4096;
    int b = blockIdx.y;
    int t = threadIdx.x, l = t & 63, w = t >> 6;
    int r0 = blockIdx.x * 128 + w * 32;  // gridDim.x = 32, 4 waves x 32 rows
    __shared__ float part[4][1024];

    float acc[2][8] = {};
    for (int r = 0; r < 32; ++r) {
        size_t row = (size_t)b * N + r0 + r;
        bf16x8 kv0 = *(const bf16x8*)&Kp[row * D + l * 8];
        bf16x8 kv1 = *(const bf16x8*)&Kp[row * D + l * 8 + 512];
        bf16x8 vv0 = *(const bf16x8*)&Vp[row * D + l * 8];
        bf16x8 vv1 = *(const bf16x8*)&Vp[row * D + l * 8 + 512];
        float kf0[8], kf1[8], ss = 0.f;
#pragma unroll
        for (int j = 0; j < 8; ++j) {
            kf0[j] = b2f((ushort)kv0[j]);
            kf1[j] = b2f((ushort)kv1[j]);
            ss += kf0[j] * kf0[j] + kf1[j] * kf1[j];
        }
#pragma unroll
        for (int off = 32; off; off >>= 1) ss += __shfl_xor(ss, off);
        float inv = 1.0f / fmaxf(sqrtf(ss), 1e-12f);
#pragma unroll
        for (int j = 0; j < 8; ++j) {
            acc[0][j] += kf0[j] * inv * b2f((ushort)vv0[j]);
            acc[1][j] += kf1[j] * inv * b2f((ushort)vv1[j]);
        }
    }
#pragma unroll
    for (int i = 0; i < 2; ++i)
#pragma unroll
        for (int j = 0; j < 8; ++j)
            part[w][l * 8 + i * 512 + j] = acc[i][j];
    __syncthreads();
    const float sc = 1.0f / 4096.0f;
#pragma unroll
    for (int i = 0; i < 4; ++i) {
        int c = t * 4 + i;
        float s = part[0][c] + part[1][c] + part[2][c] + part[3][c];
        atomicAdd(&gf[b * D + c], s * sc);
    }
}

// ---------------- out[row,e] = l2norm(Q_pre)[row,e] * gf[b,e]  (fp32 out) ---
__global__ __launch_bounds__(256) void q_scale(const ushort* __restrict__ Qp,
                                               const float* __restrict__ gf,
                                               float* __restrict__ out) {
    const int D = 1024;
    int row = blockIdx.x * 4 + (threadIdx.x >> 6);
    int l = threadIdx.x & 63;
    int b = row >> 12;  // N = 4096
    const ushort* qr = &Qp[(size_t)row * D];
    float qf[4][4];
    float ss = 0.f;
#pragma unroll
    for (int i = 0; i < 4; ++i) {
        ushort4 q = *(const ushort4*)&qr[l * 4 + i * 256];
        qf[i][0] = b2f(q.x); qf[i][1] = b2f(q.y);
        qf[i][2] = b2f(q.z); qf[i][3] = b2f(q.w);
        ss += qf[i][0] * qf[i][0] + qf[i][1] * qf[i][1] +
              qf[i][2] * qf[i][2] + qf[i][3] * qf[i][3];
    }
#pragma unroll
    for (int off = 32; off; off >>= 1) ss += __shfl_xor(ss, off);
    float inv = 1.0f / fmaxf(sqrtf(ss), 1e-12f);
#pragma unroll
    for (int i = 0; i < 4; ++i) {
        float4 g = *(const float4*)&gf[b * D + l * 4 + i * 256];
        float4 o;
        o.x = qf[i][0] * inv * g.x;
        o.y = qf[i][1] * inv * g.y;
        o.z = qf[i][2] * inv * g.z;
        o.w = qf[i][3] * inv * g.w;
        *(float4*)&out[(size_t)row * D + l * 4 + i * 256] = o;
    }
}

extern "C" void kernel_launch(void* const* d_in, const int* in_sizes, int n_in,
                              void* d_out, int out_size, void* d_ws, size_t ws_size,
                              hipStream_t stream) {
    const float* x  = (const float*)d_in[0];
    const float* Wq = (const float*)d_in[1];
    const float* Wk = (const float*)d_in[2];
    const float* Wv = (const float*)d_in[3];
    float* out = (float*)d_out;

    const int Bb = 8, Nn = 4096, D = 1024;
    const int M = Bb * Nn;  // 32768 rows

    char* ws = (char*)d_ws;
    ushort* xb  = (ushort*)ws;                         // 67108864 B
    ushort* wqb = (ushort*)(ws + 67108864);            // 2097152 B
    ushort* wkb = (ushort*)(ws + 69206016);            // 2097152 B
    ushort* wvb = (ushort*)(ws + 71303168);            // 2097152 B
    ushort* P1  = (ushort*)(ws + 73400320);            // 67108864 B (Q_pre)
    float*  gf  = (float*)(ws + 140509184);            // 32768 B

    // d_out (134.2 MB) doubles as bf16 scratch for K_pre / V until q_scale.
    ushort* Kp = (ushort*)d_out;
    ushort* Vp = Kp + (size_t)M * D;

    hipMemsetAsync(gf, 0, Bb * D * sizeof(float), stream);

    f2b_kernel<<<2048, 256, 0, stream>>>(x, xb, (M * D) / 4);
    f2b_kernel<<<256, 256, 0, stream>>>(Wq, wqb, (D * D) / 4);
    f2b_kernel<<<256, 256, 0, stream>>>(Wk, wkb, (D * D) / 4);
    f2b_kernel<<<256, 256, 0, stream>>>(Wv, wvb, (D * D) / 4);

    gemm_bt3<<<512, 512, 0, stream>>>(xb, wkb, Kp);
    gemm_bt3<<<512, 512, 0, stream>>>(xb, wvb, Vp);
    kv_reduce<<<dim3(32, 8), 256, 0, stream>>>(Kp, Vp, gf);
    gemm_bt3<<<512, 512, 0, stream>>>(xb, wqb, P1);
    q_scale<<<M / 4, 256, 0, stream>>>(P1, gf, out);
}